// Round 7
// baseline (10981.050 us; speedup 1.0000x reference)
//
#include <hip/hip_runtime.h>

// FPS: 2 batches x 131072 pts, 4096 samples/batch, seed = point 0.
// R7 = R3 (last proven-pass structure) + two placement-independent cuts:
//  (a) fire-and-forget slot store (no vmcnt(0) on the storer path);
//  (b) depth-2 software-pipelined poll: two in-flight sc0sc1 loads,
//      s_waitcnt vmcnt(1) per stage, s_sleep(1) backoff -> retry
//      quantization ~900cyc -> ~95cyc. Buffers pinned with "+v" waitcnt
//      operands; leftovers drained next step where they're already done.
// NO XCD/scope speculation, NO cross-batch coupling, NO arrival barriers
// (R4/R5/R6 all hung on placement/timing liveness bets).
//
// Protocol (proven in R3): per step, fused reg-resident dist update +
// thread argmax -> 64-lane u64 butterfly -> LDS handoff + ONE barrier ->
// wave0 lanes 0..1 store a 32B slot {key|coords} as two self-validating
// 16B quads -> ALL waves poll (lane L owns quad L; 1 load covers all 64
// quads) -> butterfly over keys -> winner coords via shfl (no dependent
// global coord load).
// Key = dist_bits<<32 | step<<17 | (0x1FFFF - idx): u64 max ==
// (dist desc, idx asc) == jnp.argmax first-index tiebreak. Exact fp32
// (contract off, __fmul_rn/__fadd_rn) matches the numpy reference.
//
// Ring safety (RING=4, fire-and-forget): block B stores s+4 only after
// passing poll(s+3), i.e. after seeing EVERY block's tag-(s+3) slot. Any
// block C still needing tag-s data would not yet have passed poll(s), so
// C never stored s+1..s+3, so nobody can have passed poll(s+3) --
// contradiction. Own-store visibility: B passes poll(s) only when its own
// slot shows tag s, so the f&f store is proven visible before B advances.
// Stale pipelined leftovers are never consumed (only drained). Zeroed or
// 0xAA-poisoned slots never tag-match (s in 1..4095).

#define NB    32
#define TPB   256
#define PPT   16      // 32*256*16 = 131072
#define NPB   131072
#define MSAMP 4096
#define RING  4

typedef unsigned long long u64;
typedef unsigned int u32;
typedef __attribute__((ext_vector_type(4))) u32 u32x4;

__device__ __forceinline__ void st16_ff(u32* p, u32x4 v) {  // fire-and-forget
  asm volatile("global_store_dwordx4 %0, %1, off sc0 sc1"
               :: "v"(p), "v"(v) : "memory");
}

__global__ __launch_bounds__(TPB, 1)
void fps_kernel(const float4* __restrict__ pts, float* __restrict__ out,
                u32* __restrict__ slots)
{
#pragma clang fp contract(off)
  const int batch = blockIdx.x >> 5;
  const int blk   = blockIdx.x & (NB - 1);
  const int tid   = threadIdx.x;
  const int lane  = tid & 63;
  const int wv    = tid >> 6;
  const float4* bpts = pts + (size_t)batch * NPB;
  u32* bslots = slots + (size_t)batch * (RING * NB * 8);  // 8 u32 per slot

  __shared__ u64   s_key[4];
  __shared__ float s_cx[4], s_cy[4], s_cz[4];

  const int base = blk * (TPB * PPT);

  float px[PPT], py[PPT], pz[PPT], dist[PPT];
#pragma unroll
  for (int k = 0; k < PPT; ++k) {
    float4 p = bpts[base + k * TPB + tid];   // row = (b, x, y, z)
    px[k] = p.y; py[k] = p.z; pz[k] = p.w;
    dist[k] = __builtin_inff();              // min(inf, d) == d bit-exactly
  }

  float4 seed = bpts[0];
  float sx = seed.y, sy = seed.z, sz = seed.w;
  if (blk == 0 && wv == 0 && lane == 0) {
    float4 o; o.x = (float)batch; o.y = sx; o.z = sy; o.w = sz;
    *(float4*)(out + (size_t)batch * MSAMP * 4) = o;
  }

  u32x4 b0 = (u32x4)(0u), b1 = (u32x4)(0u);  // pipelined poll buffers

  for (int s = 1; s < MSAMP; ++s) {
    // ---- fused dist update + per-thread argmax, coords tracked ----
    float bestd = -1.0f, bx = 0.f, by = 0.f, bz = 0.f; int besti = 0;
#pragma unroll
    for (int k = 0; k < PPT; ++k) {
      float dx = px[k] - sx, dy = py[k] - sy, dz = pz[k] - sz;
      float d2 = __fadd_rn(__fadd_rn(__fmul_rn(dx, dx), __fmul_rn(dy, dy)),
                           __fmul_rn(dz, dz));
      float nd = fminf(dist[k], d2);
      dist[k] = nd;
      if (nd > bestd) {                      // strict '>': first-index tiebreak
        bestd = nd; besti = base + k * TPB + tid;
        bx = px[k]; by = py[k]; bz = pz[k];
      }
    }

    u64 pv0 = ((u64)__float_as_uint(bestd) << 32) | ((u64)s << 17) |
              (u64)(0x1FFFF - besti);
    u64 pv = pv0;
#pragma unroll
    for (int m = 32; m >= 1; m >>= 1) {
      u64 o = __shfl_xor(pv, m, 64);
      if (o > pv) pv = o;
    }
    int wl = __ffsll(__ballot(pv0 == pv)) - 1;   // keys unique (idx embedded)
    float wx = __shfl(bx, wl, 64), wy = __shfl(by, wl, 64),
          wz = __shfl(bz, wl, 64);

    // Drain previous step's leftover in-flight poll loads (+pending f&f
    // store). Issued ~a full compute phase ago -> near-zero actual stall.
    asm volatile("s_waitcnt vmcnt(0)" : "+v"(b0), "+v"(b1) :: "memory");

    if (lane == 0) { s_key[wv] = pv; s_cx[wv] = wx; s_cy[wv] = wy; s_cz[wv] = wz; }
    __syncthreads();                         // one barrier per step

    u32* ring = bslots + (size_t)(s & (RING - 1)) * (NB * 8);
    if (wv == 0 && lane < 2) {
      u64 k0 = s_key[0], k1 = s_key[1], k2 = s_key[2], k3 = s_key[3];
      int bi = 0; u64 bk = k0;
      if (k1 > bk) { bk = k1; bi = 1; }
      if (k2 > bk) { bk = k2; bi = 2; }
      if (k3 > bk) { bk = k3; bi = 3; }
      u32x4 q;
      if (lane == 0) {                       // quad0: key(lo=tag|idx,hi=dist)+x,y
        q.x = (u32)(bk & 0xFFFFFFFFull); q.y = (u32)(bk >> 32);
        q.z = __float_as_uint(s_cx[bi]);  q.w = __float_as_uint(s_cy[bi]);
      } else {                               // quad1: tag + z
        q.x = (u32)s; q.y = __float_as_uint(s_cz[bi]); q.z = 0u; q.w = 0u;
      }
      st16_ff(ring + blk * 8 + lane * 4, q); // fire-and-forget
    }

    // ---- depth-2 pipelined poll: lane L owns quad L (slot L>>1, half L&1)
    const u32* pp = ring + lane * 4;
    asm volatile("global_load_dwordx4 %0, %1, off sc0 sc1"
                 : "=v"(b0) : "v"(pp) : "memory");
    asm volatile("global_load_dwordx4 %0, %1, off sc0 sc1"
                 : "=v"(b1) : "v"(pp) : "memory");
    u32x4 q;
    for (;;) {
      asm volatile("s_waitcnt vmcnt(1)" : "+v"(b0) :: "memory");
      q = b0;
      {
        bool ok = ((lane & 1) == 0) ? ((q.x >> 17) == (u32)s) : (q.x == (u32)s);
        if (__ballot(ok) == ~0ull) break;
      }
      asm volatile("global_load_dwordx4 %0, %1, off sc0 sc1"
                   : "=v"(b0) : "v"(pp) : "memory");
      __builtin_amdgcn_s_sleep(1);
      asm volatile("s_waitcnt vmcnt(1)" : "+v"(b1) :: "memory");
      q = b1;
      {
        bool ok = ((lane & 1) == 0) ? ((q.x >> 17) == (u32)s) : (q.x == (u32)s);
        if (__ballot(ok) == ~0ull) break;
      }
      asm volatile("global_load_dwordx4 %0, %1, off sc0 sc1"
                   : "=v"(b1) : "v"(pp) : "memory");
      __builtin_amdgcn_s_sleep(1);
    }

    // ---- cross-block argmax + register-resident coord extraction ----
    u64 key = ((lane & 1) == 0) ? (((u64)q.y << 32) | (u64)q.x) : 0ull;
    u64 w = key;
#pragma unroll
    for (int m = 32; m >= 1; m >>= 1) {
      u64 o = __shfl_xor(w, m, 64);
      if (o > w) w = o;
    }
    int wl2 = __ffsll(__ballot(key == w && ((lane & 1) == 0))) - 1;
    sx = __shfl(__uint_as_float(q.z), wl2, 64);      // x from quad0 lane
    sy = __shfl(__uint_as_float(q.w), wl2, 64);      // y from quad0 lane
    sz = __shfl(__uint_as_float(q.y), wl2 + 1, 64);  // z from quad1 lane

    if (blk == 0 && wv == 0 && lane == 0) {
      float4 o; o.x = (float)batch; o.y = sx; o.z = sy; o.w = sz;
      *(float4*)(out + (size_t)(batch * MSAMP + s) * 4) = o;
    }
  }

  // Final drain: leftover in-flight loads must complete before regs die.
  asm volatile("s_waitcnt vmcnt(0)" : "+v"(b0), "+v"(b1) :: "memory");
}

extern "C" void kernel_launch(void* const* d_in, const int* in_sizes, int n_in,
                              void* d_out, int out_size, void* d_ws, size_t ws_size,
                              hipStream_t stream) {
  const float4* pts = (const float4*)d_in[0];
  float* out = (float*)d_out;
  u32* slots = (u32*)d_ws;

  // Zero both batches' slot rings (8 KB): poisoned tags never validate.
  hipMemsetAsync(d_ws, 0, (size_t)2 * RING * NB * 32, stream);

  dim3 grid(2 * NB), block(TPB);
  hipLaunchKernelGGL(fps_kernel, grid, block, 0, stream, pts, out, slots);
}